// Round 30
// baseline (82.609 us; speedup 1.0000x reference)
//
#include <hip/hip_runtime.h>
#include <math.h>

constexpr int BATCH = 4;
constexpr int NPTS  = 8192;
constexpr int KSEL  = 16;
constexpr int G     = 24;          // 24x24 cells, ~14 pts/cell; 3x3 tile ~128 pts
constexpr int NC    = G * G;       // 576 cells
constexpr int TILE_MAX = 384;      // LDS tile capacity incl. sentinel padding (mean 128)
constexpr int TILE_USE = 320;      // stage threshold
#define CELL_W (1.0 / 24.0)

// ---- workspace layout (bytes) ----
constexpr size_t WS_HIST  = 0;        // BATCH*NC*4        = 9216
constexpr size_t WS_CURS  = 9216;     // BATCH*NC*4        = 9216
constexpr size_t WS_CSTRT = 18432;    // BATCH*(NC+1)*4    = 9232
constexpr size_t WS_PTS   = 32768;    // BATCH*NPTS*16     = 524288  (x,y,idx,sq)

#define PI_F 3.14159265358979323846f

// Fusion barrier (R17-proven): INLINEASM-defined value the DAGCombiner cannot
// contract into FMA (hipcc backend fuses fadd(fmul,fmul) even with contract(off)).
__device__ __forceinline__ float opaque(float v) { asm("" : "+v"(v)); return v; }

__device__ __forceinline__ int cell_of(float x) {
    int c = (int)(x * 24.0f);
    return c < 0 ? 0 : (c > G - 1 ? G - 1 : c);
}

// Monotone float->u32 map (d2 never -0.0/NaN in this chain). Lower j = smaller key
// on equal d2 => stable-low ties (verified reference semantics).
__device__ __forceinline__ unsigned int fkey(float f) {
    unsigned int b = __float_as_uint(f);
    return b ^ (((unsigned int)(((int)b) >> 31)) | 0x80000000u);
}
__device__ __forceinline__ float unkey(unsigned int u) {
    unsigned int b = u ^ ((u & 0x80000000u) ? 0x80000000u : 0xFFFFFFFFu);
    return __uint_as_float(b);
}

// DUAL-QUERY eval: two independent top-16 networks interleaved for ILP=2 on the
// latency-bound insert chain (R29 post-mortem: ~14cyc/instr at 1.2 waves/SIMD; the
// networks' instructions fill each other's dependency gaps). MACRO, not lambda
// (R25: by-ref capture -> scratch spill).
#define EVAL_INSERT2(PJ) do {                                                 \
    float4 _pj = (PJ);                                                        \
    int _j = __float_as_int(_pj.z);                                           \
    float _pxa = opaque(__fmul_rn(xq0, _pj.x));                               \
    float _pxb = opaque(__fmul_rn(xq1, _pj.x));                               \
    float _dta = fmaf(yq0, _pj.y, _pxa);                                      \
    float _dtb = fmaf(yq1, _pj.y, _pxb);                                      \
    float _da = __fsub_rn(__fadd_rn(sqq0, _pj.w), __fmul_rn(2.0f, _dta));     \
    float _db = __fsub_rn(__fadd_rn(sqq1, _pj.w), __fmul_rn(2.0f, _dtb));     \
    _da = (_j == qorig0) ? INFINITY : _da;                                    \
    _db = (_j == qorig1) ? INFINITY : _db;                                    \
    unsigned long long _ka =                                                  \
        ((unsigned long long)fkey(_da) << 32) | (unsigned int)_j;             \
    unsigned long long _kb =                                                  \
        ((unsigned long long)fkey(_db) << 32) | (unsigned int)_j;             \
    bool _la[KSEL], _lb[KSEL];                                                \
    _Pragma("unroll")                                                         \
    for (int _k = 0; _k < KSEL; ++_k) { _la[_k] = _ka < bk0[_k];              \
                                        _lb[_k] = _kb < bk1[_k]; }            \
    _Pragma("unroll")                                                         \
    for (int _k = KSEL - 1; _k >= 1; --_k) {                                  \
        bk0[_k] = _la[_k-1] ? bk0[_k-1] : (_la[_k] ? _ka : bk0[_k]);          \
        bk1[_k] = _lb[_k-1] ? bk1[_k-1] : (_lb[_k] ? _kb : bk1[_k]);          \
    }                                                                         \
    bk0[0] = _la[0] ? _ka : bk0[0];                                           \
    bk1[0] = _lb[0] ? _kb : bk1[0];                                           \
} while (0)

// init key: unpacks to +INF (keeps termination bound conservative).
#define INIT_KEY 0xFF800000FFFFFFFFull

// ---------------- Kernel 1: features + encode + histogram (fused) ----------------
__global__ __launch_bounds__(256) void feat_encode_hist_kernel(
    const float* __restrict__ coords, const float* __restrict__ demands,
    const float* __restrict__ capacity, const float* __restrict__ curpos,
    const float* __restrict__ Wa,  const float* __restrict__ ba,
    const float* __restrict__ W1,  const float* __restrict__ b1,
    const float* __restrict__ W2,  const float* __restrict__ b2,
    float* __restrict__ out_psi, float* __restrict__ out_feat,
    int* __restrict__ hist)
{
    int gid = blockIdx.x * blockDim.x + threadIdx.x;
    if (gid >= BATCH * NPTS) return;
    int b = gid >> 13;

    float2 c   = ((const float2*)coords)[gid];
    float2 dep = ((const float2*)coords)[(size_t)b * NPTS];
    float2 cn  = ((const float2*)curpos)[b];

    atomicAdd(&hist[b * NC + cell_of(c.y) * G + cell_of(c.x)], 1);

    float relx = c.x - dep.x, rely = c.y - dep.y;
    float dist_depot = sqrtf(relx * relx + rely * rely);
    float angle = atan2f(rely, relx) / PI_F;
    float dem = demands[gid] / capacity[b];
    float dcx = c.x - cn.x, dcy = c.y - cn.y;
    float dist_cur = sqrtf(dcx * dcx + dcy * dcy);

    float f0 = c.x, f1 = c.y, f2 = dem, f3 = dist_depot, f4 = angle, f5 = dist_cur;

    float p0 = ba[0] + f0*Wa[0] + f1*Wa[1] + f2*Wa[2]  + f3*Wa[3]  + f4*Wa[4]  + f5*Wa[5];
    float p1 = ba[1] + f0*Wa[6] + f1*Wa[7] + f2*Wa[8]  + f3*Wa[9]  + f4*Wa[10] + f5*Wa[11];
    float nrm = sqrtf(p0 * p0 + p1 * p1);
    float inv = 1.0f / (nrm + 1e-8f);
    float x = p0 * inv, y = p1 * inv;

    float theta = b2[0];
    #pragma unroll
    for (int j = 0; j < 16; ++j) {
        const float* w = W1 + j * 6;
        float hj = tanhf(b1[j] + f0*w[0] + f1*w[1] + f2*w[2] + f3*w[3] + f4*w[4] + f5*w[5]);
        theta += hj * W2[j];
    }
    float sth, cth;
    sincosf(theta, &sth, &cth);

    ((float2*)out_psi)[gid] = make_float2(cth * x - sth * y, sth * x + cth * y);
    float2* fo = (float2*)out_feat + (size_t)gid * 3;
    fo[0] = make_float2(f0, f1);
    fo[1] = make_float2(f2, f3);
    fo[2] = make_float2(f4, f5);
}

// ---------------- Grid build: 1 wave per batch, 9 cells per lane ----------------
__global__ __launch_bounds__(64) void scan_kernel(const int* __restrict__ hist,
                                                  int* __restrict__ cellStart,
                                                  int* __restrict__ cursor)
{
    int b = blockIdx.x;
    int t = threadIdx.x;                      // 0..63, cells [9t, 9t+9)
    int h[9];
    int s = 0;
    #pragma unroll
    for (int i = 0; i < 9; ++i) { h[i] = hist[b * NC + t * 9 + i]; s += h[i]; }

    int inc = s;
    #pragma unroll
    for (int d = 1; d < 64; d <<= 1) {
        int o = __shfl_up(inc, d, 64);
        if (t >= d) inc += o;
    }
    int run = inc - s;                        // exclusive prefix
    int* cs = cellStart + b * (NC + 1);
    int* cu = cursor + b * NC;
    #pragma unroll
    for (int i = 0; i < 9; ++i) {
        cs[t * 9 + i] = run;
        cu[t * 9 + i] = run;
        run += h[i];
    }
    if (t == 63) cs[NC] = run;                // = NPTS
}

__global__ __launch_bounds__(256) void scatter_kernel(const float* __restrict__ coords,
                                                      int* __restrict__ cursor,
                                                      float4* __restrict__ pts)
{
    int gid = blockIdx.x * 256 + threadIdx.x;
    if (gid >= BATCH * NPTS) return;
    int b = gid >> 13, n = gid & (NPTS - 1);
    float2 c = ((const float2*)coords)[gid];
    float sx = opaque(__fmul_rn(c.x, c.x));
    float sy = opaque(__fmul_rn(c.y, c.y));
    float sq = __fadd_rn(sx, sy);                 // unfused (a)-sq, verified chain
    int pos = atomicAdd(&cursor[b * NC + cell_of(c.y) * G + cell_of(c.x)], 1);
    pts[(b << 13) + pos] = make_float4(c.x, c.y, __int_as_float(n), sq);
}

// ---------------- Kernel 2: 1-wave-per-cell 16-NN, DUAL-QUERY ILP ----------------
// Chain (== R20-R29 PASSING, bit-exact): sq unfused (scatter), dot=fma(y,yj,round(x*xj)),
// d2 = (sqi+sqj)-2*dot, lex (d2,j) stable-low ties via u64 keys.
// Each 8-lane group owns TWO queries: two independent insert networks interleaved
// (ILP=2 fills the latency gaps R29 identified), sharing each staged cvec batch
// (halves LDS reads/query). A done-query scanning extra cells is correctness-neutral
// (superset scan). Merge/write per query. Bound/fallback semantics == R28.
__global__ __launch_bounds__(64, 2) void knn_cell_kernel(
    const int* __restrict__ cellStart, const float4* __restrict__ pts,
    float* __restrict__ out_knn)
{
    const int b    = blockIdx.y;
    const int cell = blockIdx.x;
    const int cx = cell % G, cy = cell / G;
    const int* cs = cellStart + b * (NC + 1);
    const float4* pb = pts + ((size_t)b << 13);
    const int qbeg = cs[cell], qend = cs[cell + 1];
    const int cnt = qend - qbeg;
    if (cnt == 0) return;

    __shared__ float4 tile[TILE_MAX];

    const int x0 = max(cx - 1, 0), x1 = min(cx + 1, G - 1);
    int b0 = 0, l0 = 0, b1r = 0, l1r = 0, b2 = 0, l2 = 0;
    if (cy - 1 >= 0)     { b0  = cs[(cy-1)*G + x0]; l0  = cs[(cy-1)*G + x1 + 1] - b0;  }
    {                      b1r = cs[ cy   *G + x0]; l1r = cs[ cy   *G + x1 + 1] - b1r; }
    if (cy + 1 <= G - 1) { b2  = cs[(cy+1)*G + x0]; l2  = cs[(cy+1)*G + x1 + 1] - b2;  }
    const int o1 = l0, o2 = l0 + l1r, total = o2 + l2;
    const int totalPad = (total + 63) & ~63;
    const bool useLds = (total <= TILE_USE);

    if (useLds) {
        for (int i = threadIdx.x; i < l0;  i += 64) tile[i]      = pb[b0  + i];
        for (int i = threadIdx.x; i < l1r; i += 64) tile[o1 + i] = pb[b1r + i];
        for (int i = threadIdx.x; i < l2;  i += 64) tile[o2 + i] = pb[b2  + i];
        for (int i = total + (int)threadIdx.x; i < totalPad; i += 64)
            tile[i] = make_float4(0.0f, 0.0f, __int_as_float(0x7ffffe00), INFINITY);
    }
    __syncthreads();

    const int l8  = threadIdx.x & 7;
    const int grp = threadIdx.x >> 3;             // 8 groups

    for (int qbase = 0; qbase < cnt; qbase += 16) {
        const int qi0 = qbase + grp;
        const int qi1 = qbase + grp + 8;
        const bool valid0 = (qi0 < cnt);
        const bool valid1 = (qi1 < cnt);
        if (!valid0) break;                       // group-uniform; q1 dummy-runs if invalid

        float4 me0 = pb[qbeg + qi0];
        float4 me1 = valid1 ? pb[qbeg + qi1] : me0;
        const float xq0 = me0.x, yq0 = me0.y, sqq0 = me0.w;
        const float xq1 = me1.x, yq1 = me1.y, sqq1 = me1.w;
        const int qorig0 = __float_as_int(me0.z);
        const int qorig1 = __float_as_int(me1.z);
        const double xqd0 = (double)xq0, yqd0 = (double)yq0;
        const double xqd1 = (double)xq1, yqd1 = (double)yq1;

        unsigned long long bk0[KSEL], bk1[KSEL];
        #pragma unroll
        for (int i = 0; i < KSEL; ++i) { bk0[i] = INIT_KEY; bk1[i] = INIT_KEY; }

        bool done = false;
        int mStart = 0;

        if (useLds) {
            for (int base = 0; base < totalPad; base += 64) {
                float4 cvec[8];
                #pragma unroll
                for (int i = 0; i < 8; ++i) cvec[i] = tile[base + 8 * i + l8];
                #pragma unroll
                for (int i = 0; i < 8; ++i) EVAL_INSERT2(cvec[i]);
            }
            // per-query merged bound: min(min_l bd15, max_l bd1)
            float ta = unkey((unsigned int)(bk0[KSEL-1] >> 32));
            ta = fminf(ta, __shfl_xor(ta, 1)); ta = fminf(ta, __shfl_xor(ta, 2));
            ta = fminf(ta, __shfl_xor(ta, 4));
            float ua = unkey((unsigned int)(bk0[1] >> 32));
            ua = fmaxf(ua, __shfl_xor(ua, 1)); ua = fmaxf(ua, __shfl_xor(ua, 2));
            ua = fmaxf(ua, __shfl_xor(ua, 4));
            float ub0 = fminf(ta, ua);
            float tb = unkey((unsigned int)(bk1[KSEL-1] >> 32));
            tb = fminf(tb, __shfl_xor(tb, 1)); tb = fminf(tb, __shfl_xor(tb, 2));
            tb = fminf(tb, __shfl_xor(tb, 4));
            float ubq = unkey((unsigned int)(bk1[1] >> 32));
            ubq = fmaxf(ubq, __shfl_xor(ubq, 1)); ubq = fmaxf(ubq, __shfl_xor(ubq, 2));
            ubq = fmaxf(ubq, __shfl_xor(ubq, 4));
            float ub1 = fminf(tb, ubq);

            double Rl0 = (cx - 1 > 0)     ? (xqd0 - (double)(cx - 1) * CELL_W) : INFINITY;
            double Rr0 = (cx + 1 < G - 1) ? ((double)(cx + 2) * CELL_W - xqd0) : INFINITY;
            double Rb0 = (cy - 1 > 0)     ? (yqd0 - (double)(cy - 1) * CELL_W) : INFINITY;
            double Rt0 = (cy + 1 < G - 1) ? ((double)(cy + 2) * CELL_W - yqd0) : INFINITY;
            double R0  = fmin(fmin(Rl0, Rr0), fmin(Rb0, Rt0)) - 1e-7;
            double Rl1 = (cx - 1 > 0)     ? (xqd1 - (double)(cx - 1) * CELL_W) : INFINITY;
            double Rr1 = (cx + 1 < G - 1) ? ((double)(cx + 2) * CELL_W - xqd1) : INFINITY;
            double Rb1 = (cy - 1 > 0)     ? (yqd1 - (double)(cy - 1) * CELL_W) : INFINITY;
            double Rt1 = (cy + 1 < G - 1) ? ((double)(cy + 2) * CELL_W - yqd1) : INFINITY;
            double R1  = fmin(fmin(Rl1, Rr1), fmin(Rb1, Rt1)) - 1e-7;
            done = ((double)ub0 <= R0 * R0 - 1e-5) && ((double)ub1 <= R1 * R1 - 1e-5);
            mStart = 2;
        }

        // global-memory ring fallback (rare): both queries evaluate (superset-safe)
        for (int m = mStart; m < G && !done; ++m) {
            int rx0 = max(cx - m, 0), rx1 = min(cx + m, G - 1);
            if (cy - m >= 0) {
                int cb_ = cs[(cy - m) * G + rx0], ce_ = cs[(cy - m) * G + rx1 + 1];
                for (int t = cb_ + l8; t < ce_; t += 8) EVAL_INSERT2(pb[t]);
            }
            if (m > 0 && cy + m <= G - 1) {
                int cb_ = cs[(cy + m) * G + rx0], ce_ = cs[(cy + m) * G + rx1 + 1];
                for (int t = cb_ + l8; t < ce_; t += 8) EVAL_INSERT2(pb[t]);
            }
            if (m > 0) {
                int yA = max(cy - m + 1, 0), yB = min(cy + m - 1, G - 1);
                if (cx - m >= 0)
                    for (int yy = yA; yy <= yB; ++yy) {
                        int cb_ = cs[yy * G + (cx - m)], ce_ = cs[yy * G + (cx - m) + 1];
                        for (int t = cb_ + l8; t < ce_; t += 8) EVAL_INSERT2(pb[t]);
                    }
                if (cx + m <= G - 1)
                    for (int yy = yA; yy <= yB; ++yy) {
                        int cb_ = cs[yy * G + (cx + m)], ce_ = cs[yy * G + (cx + m) + 1];
                        for (int t = cb_ + l8; t < ce_; t += 8) EVAL_INSERT2(pb[t]);
                    }
            }
            float ta = unkey((unsigned int)(bk0[KSEL-1] >> 32));
            ta = fminf(ta, __shfl_xor(ta, 1)); ta = fminf(ta, __shfl_xor(ta, 2));
            ta = fminf(ta, __shfl_xor(ta, 4));
            float ua = unkey((unsigned int)(bk0[1] >> 32));
            ua = fmaxf(ua, __shfl_xor(ua, 1)); ua = fmaxf(ua, __shfl_xor(ua, 2));
            ua = fmaxf(ua, __shfl_xor(ua, 4));
            float ub0 = fminf(ta, ua);
            float tb = unkey((unsigned int)(bk1[KSEL-1] >> 32));
            tb = fminf(tb, __shfl_xor(tb, 1)); tb = fminf(tb, __shfl_xor(tb, 2));
            tb = fminf(tb, __shfl_xor(tb, 4));
            float ubq = unkey((unsigned int)(bk1[1] >> 32));
            ubq = fmaxf(ubq, __shfl_xor(ubq, 1)); ubq = fmaxf(ubq, __shfl_xor(ubq, 2));
            ubq = fmaxf(ubq, __shfl_xor(ubq, 4));
            float ub1 = fminf(tb, ubq);

            double Rl0 = (cx - m > 0)     ? (xqd0 - (double)(cx - m) * CELL_W)     : INFINITY;
            double Rr0 = (cx + m < G - 1) ? ((double)(cx + m + 1) * CELL_W - xqd0) : INFINITY;
            double Rb0 = (cy - m > 0)     ? (yqd0 - (double)(cy - m) * CELL_W)     : INFINITY;
            double Rt0 = (cy + m < G - 1) ? ((double)(cy + m + 1) * CELL_W - yqd0) : INFINITY;
            double R0  = fmin(fmin(Rl0, Rr0), fmin(Rb0, Rt0)) - 1e-7;
            double Rl1 = (cx - m > 0)     ? (xqd1 - (double)(cx - m) * CELL_W)     : INFINITY;
            double Rr1 = (cx + m < G - 1) ? ((double)(cx + m + 1) * CELL_W - xqd1) : INFINITY;
            double Rb1 = (cy - m > 0)     ? (yqd1 - (double)(cy - m) * CELL_W)     : INFINITY;
            double Rt1 = (cy + m < G - 1) ? ((double)(cy + m + 1) * CELL_W - yqd1) : INFINITY;
            double R1  = fmin(fmin(Rl1, Rr1), fmin(Rb1, Rt1)) - 1e-7;
            if (((double)ub0 <= R0 * R0 - 1e-5) && ((double)ub1 <= R1 * R1 - 1e-5))
                done = true;
        }

        // ---- register-only lex-exact 8-list merges: 16x extract-min via butterfly ----
        {
            float v0 = 0.0f, v1 = 0.0f;
            #pragma unroll
            for (int s = 0; s < KSEL; ++s) {
                unsigned long long hk = bk0[0];
                #pragma unroll
                for (int d = 1; d < 8; d <<= 1) {
                    unsigned long long ok = __shfl_xor(hk, d);
                    hk = (ok < hk) ? ok : hk;
                }
                int hi = (int)(unsigned int)hk;
                if (2 * l8     == s) v0 = (float)hi;
                if (2 * l8 + 1 == s) v1 = (float)hi;
                if (bk0[0] == hk) {
                    #pragma unroll
                    for (int k = 0; k < KSEL - 1; ++k) bk0[k] = bk0[k+1];
                    bk0[KSEL-1] = INIT_KEY;
                }
            }
            float* o = out_knn + ((size_t)b * NPTS + qorig0) * KSEL;
            *(float2*)(o + 2 * l8) = make_float2(v0, v1);
        }
        if (valid1) {
            float v0 = 0.0f, v1 = 0.0f;
            #pragma unroll
            for (int s = 0; s < KSEL; ++s) {
                unsigned long long hk = bk1[0];
                #pragma unroll
                for (int d = 1; d < 8; d <<= 1) {
                    unsigned long long ok = __shfl_xor(hk, d);
                    hk = (ok < hk) ? ok : hk;
                }
                int hi = (int)(unsigned int)hk;
                if (2 * l8     == s) v0 = (float)hi;
                if (2 * l8 + 1 == s) v1 = (float)hi;
                if (bk1[0] == hk) {
                    #pragma unroll
                    for (int k = 0; k < KSEL - 1; ++k) bk1[k] = bk1[k+1];
                    bk1[KSEL-1] = INIT_KEY;
                }
            }
            float* o = out_knn + ((size_t)b * NPTS + qorig1) * KSEL;
            *(float2*)(o + 2 * l8) = make_float2(v0, v1);
        }
    }
}

// ---------------- launch ----------------
extern "C" void kernel_launch(void* const* d_in, const int* in_sizes, int n_in,
                              void* d_out, int out_size, void* d_ws, size_t ws_size,
                              hipStream_t stream) {
    const float* coords   = (const float*)d_in[0];
    const float* demands  = (const float*)d_in[1];
    const float* capacity = (const float*)d_in[2];
    const float* curpos   = (const float*)d_in[3];
    const float* Wa       = (const float*)d_in[4];
    const float* ba       = (const float*)d_in[5];
    const float* W1       = (const float*)d_in[6];
    const float* b1       = (const float*)d_in[7];
    const float* W2       = (const float*)d_in[8];
    const float* b2       = (const float*)d_in[9];
    // d_in[10] = knn_k (always 16, hardcoded)

    float* out      = (float*)d_out;
    float* out_psi  = out;                    // 4*8192*2  = 65536
    float* out_feat = out + 65536;            // 4*8192*6  = 196608
    float* out_knn  = out + 65536 + 196608;   // 4*8192*16 = 524288

    int*    hist      = (int*)   ((char*)d_ws + WS_HIST);
    int*    cursor    = (int*)   ((char*)d_ws + WS_CURS);
    int*    cellStart = (int*)   ((char*)d_ws + WS_CSTRT);
    float4* pts       = (float4*)((char*)d_ws + WS_PTS);

    hipMemsetAsync(hist, 0, BATCH * NC * sizeof(int), stream);

    feat_encode_hist_kernel<<<dim3((BATCH * NPTS) / 256), dim3(256), 0, stream>>>(
        coords, demands, capacity, curpos, Wa, ba, W1, b1, W2, b2, out_psi, out_feat, hist);

    scan_kernel<<<dim3(BATCH), dim3(64), 0, stream>>>(hist, cellStart, cursor);
    scatter_kernel<<<dim3((BATCH * NPTS) / 256), dim3(256), 0, stream>>>(coords, cursor, pts);

    knn_cell_kernel<<<dim3(NC, BATCH), dim3(64), 0, stream>>>(cellStart, pts, out_knn);
}

// Round 31
// 65.040 us; speedup vs baseline: 1.2701x; 1.2701x over previous
//
#include <hip/hip_runtime.h>
#include <math.h>

constexpr int BATCH = 4;
constexpr int NPTS  = 8192;
constexpr int KSEL  = 16;
constexpr int G     = 24;          // 24x24 cells, ~14 pts/cell; 3x3 tile ~128 pts
constexpr int NC    = G * G;       // 576 cells
constexpr int TILE_MAX = 384;      // LDS tile capacity incl. sentinel padding (mean 128)
constexpr int TILE_USE = 320;      // stage threshold
#define CELL_W (1.0 / 24.0)

// ---- workspace layout (bytes) ----
constexpr size_t WS_HIST  = 0;        // BATCH*NC*4        = 9216
constexpr size_t WS_CURS  = 9216;     // BATCH*NC*4        = 9216
constexpr size_t WS_CSTRT = 18432;    // BATCH*(NC+1)*4    = 9232
constexpr size_t WS_PTS   = 32768;    // BATCH*NPTS*16     = 524288  (x,y,idx,sq)

#define PI_F 3.14159265358979323846f

// Fusion barrier (R17-proven): INLINEASM-defined value the DAGCombiner cannot
// contract into FMA (hipcc backend fuses fadd(fmul,fmul) even with contract(off)).
__device__ __forceinline__ float opaque(float v) { asm("" : "+v"(v)); return v; }

__device__ __forceinline__ int cell_of(float x) {
    int c = (int)(x * 24.0f);
    return c < 0 ? 0 : (c > G - 1 ? G - 1 : c);
}

// Monotone float->u32 map (d2 never -0.0/NaN in this chain). Lower j = smaller key
// on equal d2 => stable-low ties (verified reference semantics).
__device__ __forceinline__ unsigned int fkey(float f) {
    unsigned int b = __float_as_uint(f);
    return b ^ (((unsigned int)(((int)b) >> 31)) | 0x80000000u);
}
__device__ __forceinline__ float unkey(unsigned int u) {
    unsigned int b = u ^ ((u & 0x80000000u) ? 0x80000000u : 0xFFFFFFFFu);
    return __uint_as_float(b);
}

// MACRO, not lambda (R25: by-ref capture -> scratch spill). u64 key = (fkey(d2)<<32)|j:
// lex (d2,j) compare = one v_cmp_lt_u64, slot update = 4 cndmask.
#define EVAL_INSERT(PJ) do {                                                  \
    float4 _pj = (PJ);                                                        \
    int _j = __float_as_int(_pj.z);                                           \
    float _px  = opaque(__fmul_rn(xq, _pj.x));                                \
    float _dot = fmaf(yq, _pj.y, _px);                                        \
    float _d2  = __fsub_rn(__fadd_rn(sqq, _pj.w), __fmul_rn(2.0f, _dot));     \
    _d2 = (_j == qorig) ? INFINITY : _d2;                                     \
    unsigned long long _key =                                                 \
        ((unsigned long long)fkey(_d2) << 32) | (unsigned int)_j;             \
    bool _lt[KSEL];                                                           \
    _Pragma("unroll")                                                         \
    for (int _k = 0; _k < KSEL; ++_k) _lt[_k] = _key < bk[_k];                \
    _Pragma("unroll")                                                         \
    for (int _k = KSEL - 1; _k >= 1; --_k)                                    \
        bk[_k] = _lt[_k-1] ? bk[_k-1] : (_lt[_k] ? _key : bk[_k]);            \
    bk[0] = _lt[0] ? _key : bk[0];                                            \
} while (0)

// 8-list butterfly merge (lex-exact). Records this lane's two output ranks in
// HK0/HK1 and the exact 16th-best key in D16K (group-uniform broadcast).
// Simultaneous pop across lanes dedupes identical keys.
#define MERGE_RECORD(HK0, HK1, D16K) do {                                     \
    _Pragma("unroll")                                                         \
    for (int _s = 0; _s < KSEL; ++_s) {                                       \
        unsigned long long _hk = bk[0];                                       \
        _Pragma("unroll")                                                     \
        for (int _d = 1; _d < 8; _d <<= 1) {                                  \
            unsigned long long _ok = __shfl_xor(_hk, _d);                     \
            _hk = (_ok < _hk) ? _ok : _hk;                                    \
        }                                                                     \
        if (2 * l8     == _s) (HK0) = _hk;                                    \
        if (2 * l8 + 1 == _s) (HK1) = _hk;                                    \
        if (_s == KSEL - 1)   (D16K) = _hk;                                   \
        if (bk[0] == _hk) {                                                   \
            _Pragma("unroll")                                                 \
            for (int _k = 0; _k < KSEL - 1; ++_k) bk[_k] = bk[_k+1];          \
            bk[KSEL-1] = INIT_KEY;                                            \
        }                                                                     \
    }                                                                         \
} while (0)

// init key: unpacks to +INF (keeps termination bound conservative).
#define INIT_KEY 0xFF800000FFFFFFFFull

// ---------------- Kernel 1: features + encode + histogram (fused) ----------------
__global__ __launch_bounds__(256) void feat_encode_hist_kernel(
    const float* __restrict__ coords, const float* __restrict__ demands,
    const float* __restrict__ capacity, const float* __restrict__ curpos,
    const float* __restrict__ Wa,  const float* __restrict__ ba,
    const float* __restrict__ W1,  const float* __restrict__ b1,
    const float* __restrict__ W2,  const float* __restrict__ b2,
    float* __restrict__ out_psi, float* __restrict__ out_feat,
    int* __restrict__ hist)
{
    int gid = blockIdx.x * blockDim.x + threadIdx.x;
    if (gid >= BATCH * NPTS) return;
    int b = gid >> 13;

    float2 c   = ((const float2*)coords)[gid];
    float2 dep = ((const float2*)coords)[(size_t)b * NPTS];
    float2 cn  = ((const float2*)curpos)[b];

    atomicAdd(&hist[b * NC + cell_of(c.y) * G + cell_of(c.x)], 1);

    float relx = c.x - dep.x, rely = c.y - dep.y;
    float dist_depot = sqrtf(relx * relx + rely * rely);
    float angle = atan2f(rely, relx) / PI_F;
    float dem = demands[gid] / capacity[b];
    float dcx = c.x - cn.x, dcy = c.y - cn.y;
    float dist_cur = sqrtf(dcx * dcx + dcy * dcy);

    float f0 = c.x, f1 = c.y, f2 = dem, f3 = dist_depot, f4 = angle, f5 = dist_cur;

    float p0 = ba[0] + f0*Wa[0] + f1*Wa[1] + f2*Wa[2]  + f3*Wa[3]  + f4*Wa[4]  + f5*Wa[5];
    float p1 = ba[1] + f0*Wa[6] + f1*Wa[7] + f2*Wa[8]  + f3*Wa[9]  + f4*Wa[10] + f5*Wa[11];
    float nrm = sqrtf(p0 * p0 + p1 * p1);
    float inv = 1.0f / (nrm + 1e-8f);
    float x = p0 * inv, y = p1 * inv;

    float theta = b2[0];
    #pragma unroll
    for (int j = 0; j < 16; ++j) {
        const float* w = W1 + j * 6;
        float hj = tanhf(b1[j] + f0*w[0] + f1*w[1] + f2*w[2] + f3*w[3] + f4*w[4] + f5*w[5]);
        theta += hj * W2[j];
    }
    float sth, cth;
    sincosf(theta, &sth, &cth);

    ((float2*)out_psi)[gid] = make_float2(cth * x - sth * y, sth * x + cth * y);
    float2* fo = (float2*)out_feat + (size_t)gid * 3;
    fo[0] = make_float2(f0, f1);
    fo[1] = make_float2(f2, f3);
    fo[2] = make_float2(f4, f5);
}

// ---------------- Grid build: 1 wave per batch, 9 cells per lane ----------------
__global__ __launch_bounds__(64) void scan_kernel(const int* __restrict__ hist,
                                                  int* __restrict__ cellStart,
                                                  int* __restrict__ cursor)
{
    int b = blockIdx.x;
    int t = threadIdx.x;                      // 0..63, cells [9t, 9t+9)
    int h[9];
    int s = 0;
    #pragma unroll
    for (int i = 0; i < 9; ++i) { h[i] = hist[b * NC + t * 9 + i]; s += h[i]; }

    int inc = s;
    #pragma unroll
    for (int d = 1; d < 64; d <<= 1) {
        int o = __shfl_up(inc, d, 64);
        if (t >= d) inc += o;
    }
    int run = inc - s;                        // exclusive prefix
    int* cs = cellStart + b * (NC + 1);
    int* cu = cursor + b * NC;
    #pragma unroll
    for (int i = 0; i < 9; ++i) {
        cs[t * 9 + i] = run;
        cu[t * 9 + i] = run;
        run += h[i];
    }
    if (t == 63) cs[NC] = run;                // = NPTS
}

__global__ __launch_bounds__(256) void scatter_kernel(const float* __restrict__ coords,
                                                      int* __restrict__ cursor,
                                                      float4* __restrict__ pts)
{
    int gid = blockIdx.x * 256 + threadIdx.x;
    if (gid >= BATCH * NPTS) return;
    int b = gid >> 13, n = gid & (NPTS - 1);
    float2 c = ((const float2*)coords)[gid];
    float sx = opaque(__fmul_rn(c.x, c.x));
    float sy = opaque(__fmul_rn(c.y, c.y));
    float sq = __fadd_rn(sx, sy);                 // unfused (a)-sq, verified chain
    int pos = atomicAdd(&cursor[b * NC + cell_of(c.y) * G + cell_of(c.x)], 1);
    pts[(b << 13) + pos] = make_float4(c.x, c.y, __int_as_float(n), sq);
}

// ---------------- Kernel 2: block-per-cell 16-NN, EXACT merged bound ----------------
// Chain (== R20-R30 PASSING, bit-exact). Structure = R28 (best: 53us) with the merge
// moved BEFORE the bound check: the butterfly's s=15 step broadcasts the EXACT d16,
// replacing the loose max_l bd[1] (~2.5x overestimate) that sent ~half the waves into
// the serial global m=2 ring (R28-R30's straggler tail). Bound failure prob drops to
// ~1e-4. Rare-fail path: reseed each lane's list with its two merged ranks (disjoint;
// any final-top16 element has <=15 global betters -> survives its lane's top-16),
// ring-scan m>=2, re-merge (simultaneous-pop dedupes).
__global__ __launch_bounds__(128) void knn_cell_kernel(
    const int* __restrict__ cellStart, const float4* __restrict__ pts,
    float* __restrict__ out_knn)
{
    const int b    = blockIdx.y;
    const int cell = blockIdx.x;
    const int cx = cell % G, cy = cell / G;
    const int* cs = cellStart + b * (NC + 1);
    const float4* pb = pts + ((size_t)b << 13);
    const int qbeg = cs[cell], qend = cs[cell + 1];
    const int cnt = qend - qbeg;
    if (cnt == 0) return;

    __shared__ float4 tile[TILE_MAX];

    const int x0 = max(cx - 1, 0), x1 = min(cx + 1, G - 1);
    int b0 = 0, l0 = 0, b1r = 0, l1r = 0, b2 = 0, l2 = 0;
    if (cy - 1 >= 0)     { b0  = cs[(cy-1)*G + x0]; l0  = cs[(cy-1)*G + x1 + 1] - b0;  }
    {                      b1r = cs[ cy   *G + x0]; l1r = cs[ cy   *G + x1 + 1] - b1r; }
    if (cy + 1 <= G - 1) { b2  = cs[(cy+1)*G + x0]; l2  = cs[(cy+1)*G + x1 + 1] - b2;  }
    const int o1 = l0, o2 = l0 + l1r, total = o2 + l2;
    const int totalPad = (total + 63) & ~63;
    const bool useLds = (total <= TILE_USE);

    if (useLds) {
        for (int i = threadIdx.x; i < l0;  i += 128) tile[i]      = pb[b0  + i];
        for (int i = threadIdx.x; i < l1r; i += 128) tile[o1 + i] = pb[b1r + i];
        for (int i = threadIdx.x; i < l2;  i += 128) tile[o2 + i] = pb[b2  + i];
        for (int i = total + (int)threadIdx.x; i < totalPad; i += 128)
            tile[i] = make_float4(0.0f, 0.0f, __int_as_float(0x7ffffe00), INFINITY);
    }
    __syncthreads();

    const int l8 = threadIdx.x & 7;

    for (int qi = threadIdx.x >> 3; qi < cnt; qi += 16) {
        const int p = qbeg + qi;
        float4 me = pb[p];
        const float xq = me.x, yq = me.y, sqq = me.w;
        const int qorig = __float_as_int(me.z);
        const double xqd = (double)xq, yqd = (double)yq;

        unsigned long long bk[KSEL];
        #pragma unroll
        for (int i = 0; i < KSEL; ++i) bk[i] = INIT_KEY;

        unsigned long long hk0 = INIT_KEY, hk1 = INIT_KEY, d16k = INIT_KEY;
        bool done = false;
        int mStart = 0;

        if (useLds) {
            // batch-8 register staging: amortize LDS latency over 8 candidates
            for (int base = 0; base < totalPad; base += 64) {
                float4 cvec[8];
                #pragma unroll
                for (int i = 0; i < 8; ++i) cvec[i] = tile[base + 8 * i + l8];
                #pragma unroll
                for (int i = 0; i < 8; ++i) EVAL_INSERT(cvec[i]);
            }
            // exact merged top-16 + bound
            MERGE_RECORD(hk0, hk1, d16k);
            float d16 = unkey((unsigned int)(d16k >> 32));
            double Rl = (cx - 1 > 0)     ? (xqd - (double)(cx - 1) * CELL_W) : INFINITY;
            double Rr = (cx + 1 < G - 1) ? ((double)(cx + 2) * CELL_W - xqd) : INFINITY;
            double Rb = (cy - 1 > 0)     ? (yqd - (double)(cy - 1) * CELL_W) : INFINITY;
            double Rt = (cy + 1 < G - 1) ? ((double)(cy + 2) * CELL_W - yqd) : INFINITY;
            double R  = fmin(fmin(Rl, Rr), fmin(Rb, Rt)) - 1e-7;
            done = ((double)d16 <= R * R - 1e-5);
            mStart = 2;
            if (!done) {               // reseed: lane keeps its two merged ranks
                bk[0] = hk0; bk[1] = hk1;
                #pragma unroll
                for (int i = 2; i < KSEL; ++i) bk[i] = INIT_KEY;
            }
        }

        // global-memory ring fallback (prob ~1e-4 now: exact bound)
        if (!done) {
            for (int m = mStart; m < G && !done; ++m) {
                int rx0 = max(cx - m, 0), rx1 = min(cx + m, G - 1);
                if (cy - m >= 0) {
                    int cb_ = cs[(cy - m) * G + rx0], ce_ = cs[(cy - m) * G + rx1 + 1];
                    for (int t = cb_ + l8; t < ce_; t += 8) EVAL_INSERT(pb[t]);
                }
                if (m > 0 && cy + m <= G - 1) {
                    int cb_ = cs[(cy + m) * G + rx0], ce_ = cs[(cy + m) * G + rx1 + 1];
                    for (int t = cb_ + l8; t < ce_; t += 8) EVAL_INSERT(pb[t]);
                }
                if (m > 0) {
                    int yA = max(cy - m + 1, 0), yB = min(cy + m - 1, G - 1);
                    if (cx - m >= 0)
                        for (int yy = yA; yy <= yB; ++yy) {
                            int cb_ = cs[yy * G + (cx - m)], ce_ = cs[yy * G + (cx - m) + 1];
                            for (int t = cb_ + l8; t < ce_; t += 8) EVAL_INSERT(pb[t]);
                        }
                    if (cx + m <= G - 1)
                        for (int yy = yA; yy <= yB; ++yy) {
                            int cb_ = cs[yy * G + (cx + m)], ce_ = cs[yy * G + (cx + m) + 1];
                            for (int t = cb_ + l8; t < ce_; t += 8) EVAL_INSERT(pb[t]);
                        }
                }
                // conservative cheap bound (post-reseed max_l bd[1] == exact d16)
                float t15 = unkey((unsigned int)(bk[KSEL-1] >> 32));
                t15 = fminf(t15, __shfl_xor(t15, 1));
                t15 = fminf(t15, __shfl_xor(t15, 2));
                t15 = fminf(t15, __shfl_xor(t15, 4));
                float t1 = unkey((unsigned int)(bk[1] >> 32));
                t1 = fmaxf(t1, __shfl_xor(t1, 1));
                t1 = fmaxf(t1, __shfl_xor(t1, 2));
                t1 = fmaxf(t1, __shfl_xor(t1, 4));
                float ub = fminf(t15, t1);
                double Rl = (cx - m > 0)     ? (xqd - (double)(cx - m) * CELL_W)     : INFINITY;
                double Rr = (cx + m < G - 1) ? ((double)(cx + m + 1) * CELL_W - xqd) : INFINITY;
                double Rb = (cy - m > 0)     ? (yqd - (double)(cy - m) * CELL_W)     : INFINITY;
                double Rt = (cy + m < G - 1) ? ((double)(cy + m + 1) * CELL_W - yqd) : INFINITY;
                double R  = fmin(fmin(Rl, Rr), fmin(Rb, Rt)) - 1e-7;
                if ((double)ub <= R * R - 1e-5) done = true;
            }
            MERGE_RECORD(hk0, hk1, d16k);      // re-merge (dedupes via simultaneous pop)
        }

        float v0 = (float)(int)(unsigned int)hk0;
        float v1 = (float)(int)(unsigned int)hk1;
        float* o = out_knn + ((size_t)b * NPTS + qorig) * KSEL;
        *(float2*)(o + 2 * l8) = make_float2(v0, v1);     // 8 lanes cover the 64B line
    }
}

// ---------------- launch ----------------
extern "C" void kernel_launch(void* const* d_in, const int* in_sizes, int n_in,
                              void* d_out, int out_size, void* d_ws, size_t ws_size,
                              hipStream_t stream) {
    const float* coords   = (const float*)d_in[0];
    const float* demands  = (const float*)d_in[1];
    const float* capacity = (const float*)d_in[2];
    const float* curpos   = (const float*)d_in[3];
    const float* Wa       = (const float*)d_in[4];
    const float* ba       = (const float*)d_in[5];
    const float* W1       = (const float*)d_in[6];
    const float* b1       = (const float*)d_in[7];
    const float* W2       = (const float*)d_in[8];
    const float* b2       = (const float*)d_in[9];
    // d_in[10] = knn_k (always 16, hardcoded)

    float* out      = (float*)d_out;
    float* out_psi  = out;                    // 4*8192*2  = 65536
    float* out_feat = out + 65536;            // 4*8192*6  = 196608
    float* out_knn  = out + 65536 + 196608;   // 4*8192*16 = 524288

    int*    hist      = (int*)   ((char*)d_ws + WS_HIST);
    int*    cursor    = (int*)   ((char*)d_ws + WS_CURS);
    int*    cellStart = (int*)   ((char*)d_ws + WS_CSTRT);
    float4* pts       = (float4*)((char*)d_ws + WS_PTS);

    hipMemsetAsync(hist, 0, BATCH * NC * sizeof(int), stream);

    feat_encode_hist_kernel<<<dim3((BATCH * NPTS) / 256), dim3(256), 0, stream>>>(
        coords, demands, capacity, curpos, Wa, ba, W1, b1, W2, b2, out_psi, out_feat, hist);

    scan_kernel<<<dim3(BATCH), dim3(64), 0, stream>>>(hist, cellStart, cursor);
    scatter_kernel<<<dim3((BATCH * NPTS) / 256), dim3(256), 0, stream>>>(coords, cursor, pts);

    knn_cell_kernel<<<dim3(NC, BATCH), dim3(128), 0, stream>>>(cellStart, pts, out_knn);
}

// Round 32
// 61.495 us; speedup vs baseline: 1.3433x; 1.0577x over previous
//
#include <hip/hip_runtime.h>
#include <math.h>

constexpr int BATCH = 4;
constexpr int NPTS  = 8192;
constexpr int KSEL  = 16;
constexpr int G     = 24;          // 24x24 cells, ~14 pts/cell; 3x3 tile ~128 pts
constexpr int NC    = G * G;       // 576 cells
constexpr int TILE_MAX = 384;      // LDS tile capacity incl. sentinel padding (mean 128)
constexpr int TILE_USE = 320;      // stage threshold
#define CELL_W (1.0 / 24.0)

// ---- workspace layout (bytes) ----
constexpr size_t WS_CSTRT = 0;        // BATCH*(NC+1)*4    = 9232
constexpr size_t WS_PTS   = 16384;    // BATCH*NPTS*16     = 524288  (x,y,idx,sq)

#define PI_F 3.14159265358979323846f

// Fusion barrier (R17-proven): INLINEASM-defined value the DAGCombiner cannot
// contract into FMA (hipcc backend fuses fadd(fmul,fmul) even with contract(off)).
__device__ __forceinline__ float opaque(float v) { asm("" : "+v"(v)); return v; }

__device__ __forceinline__ int cell_of(float x) {
    int c = (int)(x * 24.0f);
    return c < 0 ? 0 : (c > G - 1 ? G - 1 : c);
}

// Monotone float->u32 map (d2 never -0.0/NaN in this chain). Lower j = smaller key
// on equal d2 => stable-low ties (verified reference semantics).
__device__ __forceinline__ unsigned int fkey(float f) {
    unsigned int b = __float_as_uint(f);
    return b ^ (((unsigned int)(((int)b) >> 31)) | 0x80000000u);
}
__device__ __forceinline__ float unkey(unsigned int u) {
    unsigned int b = u ^ ((u & 0x80000000u) ? 0x80000000u : 0xFFFFFFFFu);
    return __uint_as_float(b);
}

// MACRO, not lambda (R25: by-ref capture -> scratch spill). u64 key = (fkey(d2)<<32)|j:
// lex (d2,j) compare = one v_cmp_lt_u64, slot update = 4 cndmask.
#define EVAL_INSERT(PJ) do {                                                  \
    float4 _pj = (PJ);                                                        \
    int _j = __float_as_int(_pj.z);                                           \
    float _px  = opaque(__fmul_rn(xq, _pj.x));                                \
    float _dot = fmaf(yq, _pj.y, _px);                                        \
    float _d2  = __fsub_rn(__fadd_rn(sqq, _pj.w), __fmul_rn(2.0f, _dot));     \
    _d2 = (_j == qorig) ? INFINITY : _d2;                                     \
    unsigned long long _key =                                                 \
        ((unsigned long long)fkey(_d2) << 32) | (unsigned int)_j;             \
    bool _lt[KSEL];                                                           \
    _Pragma("unroll")                                                         \
    for (int _k = 0; _k < KSEL; ++_k) _lt[_k] = _key < bk[_k];                \
    _Pragma("unroll")                                                         \
    for (int _k = KSEL - 1; _k >= 1; --_k)                                    \
        bk[_k] = _lt[_k-1] ? bk[_k-1] : (_lt[_k] ? _key : bk[_k]);            \
    bk[0] = _lt[0] ? _key : bk[0];                                            \
} while (0)

// 8-list butterfly merge (lex-exact): lane's two output ranks + exact 16th-best key.
#define MERGE_RECORD(HK0, HK1, D16K) do {                                     \
    _Pragma("unroll")                                                         \
    for (int _s = 0; _s < KSEL; ++_s) {                                       \
        unsigned long long _hk = bk[0];                                       \
        _Pragma("unroll")                                                     \
        for (int _d = 1; _d < 8; _d <<= 1) {                                  \
            unsigned long long _ok = __shfl_xor(_hk, _d);                     \
            _hk = (_ok < _hk) ? _ok : _hk;                                    \
        }                                                                     \
        if (2 * l8     == _s) (HK0) = _hk;                                    \
        if (2 * l8 + 1 == _s) (HK1) = _hk;                                    \
        if (_s == KSEL - 1)   (D16K) = _hk;                                   \
        if (bk[0] == _hk) {                                                   \
            _Pragma("unroll")                                                 \
            for (int _k = 0; _k < KSEL - 1; ++_k) bk[_k] = bk[_k+1];          \
            bk[KSEL-1] = INIT_KEY;                                            \
        }                                                                     \
    }                                                                         \
} while (0)

// init key: unpacks to +INF (keeps termination bound conservative).
#define INIT_KEY 0xFF800000FFFFFFFFull

// ---------------- Kernel 1: features + encode (hist removed -> fused grid build) ----------
__global__ __launch_bounds__(256) void feat_encode_kernel(
    const float* __restrict__ coords, const float* __restrict__ demands,
    const float* __restrict__ capacity, const float* __restrict__ curpos,
    const float* __restrict__ Wa,  const float* __restrict__ ba,
    const float* __restrict__ W1,  const float* __restrict__ b1,
    const float* __restrict__ W2,  const float* __restrict__ b2,
    float* __restrict__ out_psi, float* __restrict__ out_feat)
{
    int gid = blockIdx.x * blockDim.x + threadIdx.x;
    if (gid >= BATCH * NPTS) return;
    int b = gid >> 13;

    float2 c   = ((const float2*)coords)[gid];
    float2 dep = ((const float2*)coords)[(size_t)b * NPTS];
    float2 cn  = ((const float2*)curpos)[b];

    float relx = c.x - dep.x, rely = c.y - dep.y;
    float dist_depot = sqrtf(relx * relx + rely * rely);
    float angle = atan2f(rely, relx) / PI_F;
    float dem = demands[gid] / capacity[b];
    float dcx = c.x - cn.x, dcy = c.y - cn.y;
    float dist_cur = sqrtf(dcx * dcx + dcy * dcy);

    float f0 = c.x, f1 = c.y, f2 = dem, f3 = dist_depot, f4 = angle, f5 = dist_cur;

    float p0 = ba[0] + f0*Wa[0] + f1*Wa[1] + f2*Wa[2]  + f3*Wa[3]  + f4*Wa[4]  + f5*Wa[5];
    float p1 = ba[1] + f0*Wa[6] + f1*Wa[7] + f2*Wa[8]  + f3*Wa[9]  + f4*Wa[10] + f5*Wa[11];
    float nrm = sqrtf(p0 * p0 + p1 * p1);
    float inv = 1.0f / (nrm + 1e-8f);
    float x = p0 * inv, y = p1 * inv;

    float theta = b2[0];
    #pragma unroll
    for (int j = 0; j < 16; ++j) {
        const float* w = W1 + j * 6;
        float hj = tanhf(b1[j] + f0*w[0] + f1*w[1] + f2*w[2] + f3*w[3] + f4*w[4] + f5*w[5]);
        theta += hj * W2[j];
    }
    float sth, cth;
    sincosf(theta, &sth, &cth);

    ((float2*)out_psi)[gid] = make_float2(cth * x - sth * y, sth * x + cth * y);
    float2* fo = (float2*)out_feat + (size_t)gid * 3;
    fo[0] = make_float2(f0, f1);
    fo[1] = make_float2(f2, f3);
    fo[2] = make_float2(f4, f5);
}

// ---------------- Fused grid build: hist + scan + scatter, 1 block per batch ------------
// LDS histogram (576 cells) -> in-LDS wave scan (9 cells/lane, same verified scan) ->
// LDS-cursor scatter. Replaces memset + global-hist atomics + scan + scatter dispatches.
__global__ __launch_bounds__(256) void grid_build_kernel(
    const float* __restrict__ coords,
    int* __restrict__ cellStart, float4* __restrict__ pts)
{
    const int b = blockIdx.x;
    const float2* cb = (const float2*)coords + (size_t)b * NPTS;
    float4* po = pts + ((size_t)b << 13);

    __shared__ int shist[NC];
    __shared__ int scur[NC];

    for (int i = threadIdx.x; i < NC; i += 256) shist[i] = 0;
    __syncthreads();

    for (int i = threadIdx.x; i < NPTS; i += 256) {
        float2 c = cb[i];
        atomicAdd(&shist[cell_of(c.y) * G + cell_of(c.x)], 1);
    }
    __syncthreads();

    if (threadIdx.x < 64) {
        int t = threadIdx.x;                  // cells [9t, 9t+9)
        int h[9];
        int s = 0;
        #pragma unroll
        for (int i = 0; i < 9; ++i) { h[i] = shist[t * 9 + i]; s += h[i]; }
        int inc = s;
        #pragma unroll
        for (int d = 1; d < 64; d <<= 1) {
            int o = __shfl_up(inc, d, 64);
            if (t >= d) inc += o;
        }
        int run = inc - s;                    // exclusive prefix
        int* cs = cellStart + b * (NC + 1);
        #pragma unroll
        for (int i = 0; i < 9; ++i) {
            cs[t * 9 + i] = run;
            scur[t * 9 + i] = run;
            run += h[i];
        }
        if (t == 63) cs[NC] = run;            // = NPTS
    }
    __syncthreads();

    for (int i = threadIdx.x; i < NPTS; i += 256) {
        float2 c = cb[i];
        float sx = opaque(__fmul_rn(c.x, c.x));
        float sy = opaque(__fmul_rn(c.y, c.y));
        float sq = __fadd_rn(sx, sy);             // unfused (a)-sq, verified chain
        int pos = atomicAdd(&scur[cell_of(c.y) * G + cell_of(c.x)], 1);
        po[pos] = make_float4(c.x, c.y, __int_as_float(i), sq);
    }
}

// ---------------- Kernel 2: parity-split block-per-cell 16-NN, exact merged bound --------
// Chain (== R20-R31 PASSING, bit-exact). Structure = R31 (exact-d16 bound + reseed
// fallback) + parity split (blockIdx.z): 16 groups cover cnt<=32 in ONE guaranteed pass,
// removing the 2-pass stragglers (P(cnt>16) ~ 30% at Poisson(14.2)) R31's 14% occupancy
// tail pointed at; 4608 blocks improve packing.
__global__ __launch_bounds__(128) void knn_cell_kernel(
    const int* __restrict__ cellStart, const float4* __restrict__ pts,
    float* __restrict__ out_knn)
{
    const int b    = blockIdx.y;
    const int cell = blockIdx.x;
    const int half = blockIdx.z;                  // 0/1: qi parity
    const int cx = cell % G, cy = cell / G;
    const int* cs = cellStart + b * (NC + 1);
    const float4* pb = pts + ((size_t)b << 13);
    const int qbeg = cs[cell], qend = cs[cell + 1];
    const int cnt = qend - qbeg;
    if (cnt <= half) return;

    __shared__ float4 tile[TILE_MAX];

    const int x0 = max(cx - 1, 0), x1 = min(cx + 1, G - 1);
    int b0 = 0, l0 = 0, b1r = 0, l1r = 0, b2 = 0, l2 = 0;
    if (cy - 1 >= 0)     { b0  = cs[(cy-1)*G + x0]; l0  = cs[(cy-1)*G + x1 + 1] - b0;  }
    {                      b1r = cs[ cy   *G + x0]; l1r = cs[ cy   *G + x1 + 1] - b1r; }
    if (cy + 1 <= G - 1) { b2  = cs[(cy+1)*G + x0]; l2  = cs[(cy+1)*G + x1 + 1] - b2;  }
    const int o1 = l0, o2 = l0 + l1r, total = o2 + l2;
    const int totalPad = (total + 63) & ~63;
    const bool useLds = (total <= TILE_USE);

    if (useLds) {
        for (int i = threadIdx.x; i < l0;  i += 128) tile[i]      = pb[b0  + i];
        for (int i = threadIdx.x; i < l1r; i += 128) tile[o1 + i] = pb[b1r + i];
        for (int i = threadIdx.x; i < l2;  i += 128) tile[o2 + i] = pb[b2  + i];
        for (int i = total + (int)threadIdx.x; i < totalPad; i += 128)
            tile[i] = make_float4(0.0f, 0.0f, __int_as_float(0x7ffffe00), INFINITY);
    }
    __syncthreads();

    const int l8 = threadIdx.x & 7;

    for (int qi = 2 * (threadIdx.x >> 3) + half; qi < cnt; qi += 32) {
        const int p = qbeg + qi;
        float4 me = pb[p];
        const float xq = me.x, yq = me.y, sqq = me.w;
        const int qorig = __float_as_int(me.z);
        const double xqd = (double)xq, yqd = (double)yq;

        unsigned long long bk[KSEL];
        #pragma unroll
        for (int i = 0; i < KSEL; ++i) bk[i] = INIT_KEY;

        unsigned long long hk0 = INIT_KEY, hk1 = INIT_KEY, d16k = INIT_KEY;
        bool done = false;
        int mStart = 0;

        if (useLds) {
            for (int base = 0; base < totalPad; base += 64) {
                float4 cvec[8];
                #pragma unroll
                for (int i = 0; i < 8; ++i) cvec[i] = tile[base + 8 * i + l8];
                #pragma unroll
                for (int i = 0; i < 8; ++i) EVAL_INSERT(cvec[i]);
            }
            MERGE_RECORD(hk0, hk1, d16k);       // exact merged top-16
            float d16 = unkey((unsigned int)(d16k >> 32));
            double Rl = (cx - 1 > 0)     ? (xqd - (double)(cx - 1) * CELL_W) : INFINITY;
            double Rr = (cx + 1 < G - 1) ? ((double)(cx + 2) * CELL_W - xqd) : INFINITY;
            double Rb = (cy - 1 > 0)     ? (yqd - (double)(cy - 1) * CELL_W) : INFINITY;
            double Rt = (cy + 1 < G - 1) ? ((double)(cy + 2) * CELL_W - yqd) : INFINITY;
            double R  = fmin(fmin(Rl, Rr), fmin(Rb, Rt)) - 1e-7;
            done = ((double)d16 <= R * R - 1e-5);
            mStart = 2;
            if (!done) {                         // reseed with this lane's two ranks
                bk[0] = hk0; bk[1] = hk1;
                #pragma unroll
                for (int i = 2; i < KSEL; ++i) bk[i] = INIT_KEY;
            }
        }

        if (!done) {                             // rare (prob ~1e-4): global ring scan
            for (int m = mStart; m < G && !done; ++m) {
                int rx0 = max(cx - m, 0), rx1 = min(cx + m, G - 1);
                if (cy - m >= 0) {
                    int cb_ = cs[(cy - m) * G + rx0], ce_ = cs[(cy - m) * G + rx1 + 1];
                    for (int t = cb_ + l8; t < ce_; t += 8) EVAL_INSERT(pb[t]);
                }
                if (m > 0 && cy + m <= G - 1) {
                    int cb_ = cs[(cy + m) * G + rx0], ce_ = cs[(cy + m) * G + rx1 + 1];
                    for (int t = cb_ + l8; t < ce_; t += 8) EVAL_INSERT(pb[t]);
                }
                if (m > 0) {
                    int yA = max(cy - m + 1, 0), yB = min(cy + m - 1, G - 1);
                    if (cx - m >= 0)
                        for (int yy = yA; yy <= yB; ++yy) {
                            int cb_ = cs[yy * G + (cx - m)], ce_ = cs[yy * G + (cx - m) + 1];
                            for (int t = cb_ + l8; t < ce_; t += 8) EVAL_INSERT(pb[t]);
                        }
                    if (cx + m <= G - 1)
                        for (int yy = yA; yy <= yB; ++yy) {
                            int cb_ = cs[yy * G + (cx + m)], ce_ = cs[yy * G + (cx + m) + 1];
                            for (int t = cb_ + l8; t < ce_; t += 8) EVAL_INSERT(pb[t]);
                        }
                }
                float t15 = unkey((unsigned int)(bk[KSEL-1] >> 32));
                t15 = fminf(t15, __shfl_xor(t15, 1));
                t15 = fminf(t15, __shfl_xor(t15, 2));
                t15 = fminf(t15, __shfl_xor(t15, 4));
                float t1 = unkey((unsigned int)(bk[1] >> 32));
                t1 = fmaxf(t1, __shfl_xor(t1, 1));
                t1 = fmaxf(t1, __shfl_xor(t1, 2));
                t1 = fmaxf(t1, __shfl_xor(t1, 4));
                float ub = fminf(t15, t1);
                double Rl = (cx - m > 0)     ? (xqd - (double)(cx - m) * CELL_W)     : INFINITY;
                double Rr = (cx + m < G - 1) ? ((double)(cx + m + 1) * CELL_W - xqd) : INFINITY;
                double Rb = (cy - m > 0)     ? (yqd - (double)(cy - m) * CELL_W)     : INFINITY;
                double Rt = (cy + m < G - 1) ? ((double)(cy + m + 1) * CELL_W - yqd) : INFINITY;
                double R  = fmin(fmin(Rl, Rr), fmin(Rb, Rt)) - 1e-7;
                if ((double)ub <= R * R - 1e-5) done = true;
            }
            MERGE_RECORD(hk0, hk1, d16k);        // re-merge (simultaneous-pop dedupes)
        }

        float v0 = (float)(int)(unsigned int)hk0;
        float v1 = (float)(int)(unsigned int)hk1;
        float* o = out_knn + ((size_t)b * NPTS + qorig) * KSEL;
        *(float2*)(o + 2 * l8) = make_float2(v0, v1);     // 8 lanes cover the 64B line
    }
}

// ---------------- launch ----------------
extern "C" void kernel_launch(void* const* d_in, const int* in_sizes, int n_in,
                              void* d_out, int out_size, void* d_ws, size_t ws_size,
                              hipStream_t stream) {
    const float* coords   = (const float*)d_in[0];
    const float* demands  = (const float*)d_in[1];
    const float* capacity = (const float*)d_in[2];
    const float* curpos   = (const float*)d_in[3];
    const float* Wa       = (const float*)d_in[4];
    const float* ba       = (const float*)d_in[5];
    const float* W1       = (const float*)d_in[6];
    const float* b1       = (const float*)d_in[7];
    const float* W2       = (const float*)d_in[8];
    const float* b2       = (const float*)d_in[9];
    // d_in[10] = knn_k (always 16, hardcoded)

    float* out      = (float*)d_out;
    float* out_psi  = out;                    // 4*8192*2  = 65536
    float* out_feat = out + 65536;            // 4*8192*6  = 196608
    float* out_knn  = out + 65536 + 196608;   // 4*8192*16 = 524288

    int*    cellStart = (int*)   ((char*)d_ws + WS_CSTRT);
    float4* pts       = (float4*)((char*)d_ws + WS_PTS);

    feat_encode_kernel<<<dim3((BATCH * NPTS) / 256), dim3(256), 0, stream>>>(
        coords, demands, capacity, curpos, Wa, ba, W1, b1, W2, b2, out_psi, out_feat);

    grid_build_kernel<<<dim3(BATCH), dim3(256), 0, stream>>>(coords, cellStart, pts);

    knn_cell_kernel<<<dim3(NC, BATCH, 2), dim3(128), 0, stream>>>(cellStart, pts, out_knn);
}

// Round 33
// 57.594 us; speedup vs baseline: 1.4343x; 1.0677x over previous
//
#include <hip/hip_runtime.h>
#include <math.h>

constexpr int BATCH = 4;
constexpr int NPTS  = 8192;
constexpr int KSEL  = 16;
constexpr int G     = 24;          // 24x24 cells, ~14 pts/cell; 3x3 tile ~128 pts
constexpr int NC    = G * G;       // 576 cells
constexpr int TILE_MAX = 384;      // LDS tile capacity incl. sentinel padding (mean 128)
constexpr int TILE_USE = 320;      // stage threshold
#define CELL_W (1.0 / 24.0)

// ---- workspace layout (bytes) ----
constexpr size_t WS_CSTRT = 0;        // BATCH*(NC+1)*4    = 9232
constexpr size_t WS_CURS  = 9232;     // BATCH*NC*4        = 9216 (padded to 16384 below)
constexpr size_t WS_PTS   = 32768;    // BATCH*NPTS*16     = 524288  (x,y,idx,sq)

#define PI_F 3.14159265358979323846f

// Fusion barrier (R17-proven): INLINEASM-defined value the DAGCombiner cannot
// contract into FMA (hipcc backend fuses fadd(fmul,fmul) even with contract(off)).
__device__ __forceinline__ float opaque(float v) { asm("" : "+v"(v)); return v; }

__device__ __forceinline__ int cell_of(float x) {
    int c = (int)(x * 24.0f);
    return c < 0 ? 0 : (c > G - 1 ? G - 1 : c);
}

// Monotone float->u32 map (d2 never -0.0/NaN in this chain). Lower j = smaller key
// on equal d2 => stable-low ties (verified reference semantics).
__device__ __forceinline__ unsigned int fkey(float f) {
    unsigned int b = __float_as_uint(f);
    return b ^ (((unsigned int)(((int)b) >> 31)) | 0x80000000u);
}
__device__ __forceinline__ float unkey(unsigned int u) {
    unsigned int b = u ^ ((u & 0x80000000u) ? 0x80000000u : 0xFFFFFFFFu);
    return __uint_as_float(b);
}

// MACRO, not lambda (R25: by-ref capture -> scratch spill). u64 key = (fkey(d2)<<32)|j:
// lex (d2,j) compare = one v_cmp_lt_u64, slot update = 4 cndmask.
#define EVAL_INSERT(PJ) do {                                                  \
    float4 _pj = (PJ);                                                        \
    int _j = __float_as_int(_pj.z);                                           \
    float _px  = opaque(__fmul_rn(xq, _pj.x));                                \
    float _dot = fmaf(yq, _pj.y, _px);                                        \
    float _d2  = __fsub_rn(__fadd_rn(sqq, _pj.w), __fmul_rn(2.0f, _dot));     \
    _d2 = (_j == qorig) ? INFINITY : _d2;                                     \
    unsigned long long _key =                                                 \
        ((unsigned long long)fkey(_d2) << 32) | (unsigned int)_j;             \
    bool _lt[KSEL];                                                           \
    _Pragma("unroll")                                                         \
    for (int _k = 0; _k < KSEL; ++_k) _lt[_k] = _key < bk[_k];                \
    _Pragma("unroll")                                                         \
    for (int _k = KSEL - 1; _k >= 1; --_k)                                    \
        bk[_k] = _lt[_k-1] ? bk[_k-1] : (_lt[_k] ? _key : bk[_k]);            \
    bk[0] = _lt[0] ? _key : bk[0];                                            \
} while (0)

// 8-list butterfly merge (lex-exact): lane's two output ranks + exact 16th-best key.
#define MERGE_RECORD(HK0, HK1, D16K) do {                                     \
    _Pragma("unroll")                                                         \
    for (int _s = 0; _s < KSEL; ++_s) {                                       \
        unsigned long long _hk = bk[0];                                       \
        _Pragma("unroll")                                                     \
        for (int _d = 1; _d < 8; _d <<= 1) {                                  \
            unsigned long long _ok = __shfl_xor(_hk, _d);                     \
            _hk = (_ok < _hk) ? _ok : _hk;                                    \
        }                                                                     \
        if (2 * l8     == _s) (HK0) = _hk;                                    \
        if (2 * l8 + 1 == _s) (HK1) = _hk;                                    \
        if (_s == KSEL - 1)   (D16K) = _hk;                                   \
        if (bk[0] == _hk) {                                                   \
            _Pragma("unroll")                                                 \
            for (int _k = 0; _k < KSEL - 1; ++_k) bk[_k] = bk[_k+1];          \
            bk[KSEL-1] = INIT_KEY;                                            \
        }                                                                     \
    }                                                                         \
} while (0)

// init key: unpacks to +INF (keeps termination bound conservative).
#define INIT_KEY 0xFF800000FFFFFFFFull

// ---------------- Kernel A: hist + scan only (4 blocks; scatter moved out) ----------------
// R32 post-mortem: the fused 4-block grid_build serialized ~8us of scattered stores on
// 4 CUs. Here the 4-block kernel does only the cheap LDS hist + wave scan, writing
// cellStart and a global cursor copy; the expensive per-point work moves to Kernel B.
__global__ __launch_bounds__(256) void grid_hist_scan_kernel(
    const float* __restrict__ coords,
    int* __restrict__ cellStart, int* __restrict__ cursor)
{
    const int b = blockIdx.x;
    const float2* cb = (const float2*)coords + (size_t)b * NPTS;

    __shared__ int shist[NC];
    for (int i = threadIdx.x; i < NC; i += 256) shist[i] = 0;
    __syncthreads();

    for (int i = threadIdx.x; i < NPTS; i += 256) {
        float2 c = cb[i];
        atomicAdd(&shist[cell_of(c.y) * G + cell_of(c.x)], 1);
    }
    __syncthreads();

    if (threadIdx.x < 64) {
        int t = threadIdx.x;                  // cells [9t, 9t+9)
        int h[9];
        int s = 0;
        #pragma unroll
        for (int i = 0; i < 9; ++i) { h[i] = shist[t * 9 + i]; s += h[i]; }
        int inc = s;
        #pragma unroll
        for (int d = 1; d < 64; d <<= 1) {
            int o = __shfl_up(inc, d, 64);
            if (t >= d) inc += o;
        }
        int run = inc - s;                    // exclusive prefix
        int* cs = cellStart + b * (NC + 1);
        int* cu = cursor + b * NC;
        #pragma unroll
        for (int i = 0; i < 9; ++i) {
            cs[t * 9 + i] = run;
            cu[t * 9 + i] = run;
            run += h[i];
        }
        if (t == 63) cs[NC] = run;            // = NPTS
    }
}

// ---------------- Kernel B: features + encode + scatter (fused; 128 blocks) --------------
// Both passes iterate every point exactly once -> fuse them. Scatter order across blocks
// is nondeterministic (device-scope atomics) but harmless: the knn selection uses the
// order-independent lex (d2,j) compare (verified bit-identical grid<->brute since R20).
__global__ __launch_bounds__(256) void feat_scatter_kernel(
    const float* __restrict__ coords, const float* __restrict__ demands,
    const float* __restrict__ capacity, const float* __restrict__ curpos,
    const float* __restrict__ Wa,  const float* __restrict__ ba,
    const float* __restrict__ W1,  const float* __restrict__ b1,
    const float* __restrict__ W2,  const float* __restrict__ b2,
    float* __restrict__ out_psi, float* __restrict__ out_feat,
    int* __restrict__ cursor, float4* __restrict__ pts)
{
    int gid = blockIdx.x * blockDim.x + threadIdx.x;
    if (gid >= BATCH * NPTS) return;
    int b = gid >> 13, n = gid & (NPTS - 1);

    float2 c   = ((const float2*)coords)[gid];
    float2 dep = ((const float2*)coords)[(size_t)b * NPTS];
    float2 cn  = ((const float2*)curpos)[b];

    // ---- scatter (verified unfused (a)-sq chain) ----
    float sx = opaque(__fmul_rn(c.x, c.x));
    float sy = opaque(__fmul_rn(c.y, c.y));
    float sq = __fadd_rn(sx, sy);
    int pos = atomicAdd(&cursor[b * NC + cell_of(c.y) * G + cell_of(c.x)], 1);
    pts[(b << 13) + pos] = make_float4(c.x, c.y, __int_as_float(n), sq);

    // ---- features + encode (passed R20-R32, untouched math) ----
    float relx = c.x - dep.x, rely = c.y - dep.y;
    float dist_depot = sqrtf(relx * relx + rely * rely);
    float angle = atan2f(rely, relx) / PI_F;
    float dem = demands[gid] / capacity[b];
    float dcx = c.x - cn.x, dcy = c.y - cn.y;
    float dist_cur = sqrtf(dcx * dcx + dcy * dcy);

    float f0 = c.x, f1 = c.y, f2 = dem, f3 = dist_depot, f4 = angle, f5 = dist_cur;

    float p0 = ba[0] + f0*Wa[0] + f1*Wa[1] + f2*Wa[2]  + f3*Wa[3]  + f4*Wa[4]  + f5*Wa[5];
    float p1 = ba[1] + f0*Wa[6] + f1*Wa[7] + f2*Wa[8]  + f3*Wa[9]  + f4*Wa[10] + f5*Wa[11];
    float nrm = sqrtf(p0 * p0 + p1 * p1);
    float inv = 1.0f / (nrm + 1e-8f);
    float x = p0 * inv, y = p1 * inv;

    float theta = b2[0];
    #pragma unroll
    for (int j = 0; j < 16; ++j) {
        const float* w = W1 + j * 6;
        float hj = tanhf(b1[j] + f0*w[0] + f1*w[1] + f2*w[2] + f3*w[3] + f4*w[4] + f5*w[5]);
        theta += hj * W2[j];
    }
    float sth, cth;
    sincosf(theta, &sth, &cth);

    ((float2*)out_psi)[gid] = make_float2(cth * x - sth * y, sth * x + cth * y);
    float2* fo = (float2*)out_feat + (size_t)gid * 3;
    fo[0] = make_float2(f0, f1);
    fo[1] = make_float2(f2, f3);
    fo[2] = make_float2(f4, f5);
}

// ---------------- Kernel C: parity-split block-per-cell 16-NN (== R32, PASSED) -----------
__global__ __launch_bounds__(128) void knn_cell_kernel(
    const int* __restrict__ cellStart, const float4* __restrict__ pts,
    float* __restrict__ out_knn)
{
    const int b    = blockIdx.y;
    const int cell = blockIdx.x;
    const int half = blockIdx.z;                  // 0/1: qi parity
    const int cx = cell % G, cy = cell / G;
    const int* cs = cellStart + b * (NC + 1);
    const float4* pb = pts + ((size_t)b << 13);
    const int qbeg = cs[cell], qend = cs[cell + 1];
    const int cnt = qend - qbeg;
    if (cnt <= half) return;

    __shared__ float4 tile[TILE_MAX];

    const int x0 = max(cx - 1, 0), x1 = min(cx + 1, G - 1);
    int b0 = 0, l0 = 0, b1r = 0, l1r = 0, b2 = 0, l2 = 0;
    if (cy - 1 >= 0)     { b0  = cs[(cy-1)*G + x0]; l0  = cs[(cy-1)*G + x1 + 1] - b0;  }
    {                      b1r = cs[ cy   *G + x0]; l1r = cs[ cy   *G + x1 + 1] - b1r; }
    if (cy + 1 <= G - 1) { b2  = cs[(cy+1)*G + x0]; l2  = cs[(cy+1)*G + x1 + 1] - b2;  }
    const int o1 = l0, o2 = l0 + l1r, total = o2 + l2;
    const int totalPad = (total + 63) & ~63;
    const bool useLds = (total <= TILE_USE);

    if (useLds) {
        for (int i = threadIdx.x; i < l0;  i += 128) tile[i]      = pb[b0  + i];
        for (int i = threadIdx.x; i < l1r; i += 128) tile[o1 + i] = pb[b1r + i];
        for (int i = threadIdx.x; i < l2;  i += 128) tile[o2 + i] = pb[b2  + i];
        for (int i = total + (int)threadIdx.x; i < totalPad; i += 128)
            tile[i] = make_float4(0.0f, 0.0f, __int_as_float(0x7ffffe00), INFINITY);
    }
    __syncthreads();

    const int l8 = threadIdx.x & 7;

    for (int qi = 2 * (threadIdx.x >> 3) + half; qi < cnt; qi += 32) {
        const int p = qbeg + qi;
        float4 me = pb[p];
        const float xq = me.x, yq = me.y, sqq = me.w;
        const int qorig = __float_as_int(me.z);
        const double xqd = (double)xq, yqd = (double)yq;

        unsigned long long bk[KSEL];
        #pragma unroll
        for (int i = 0; i < KSEL; ++i) bk[i] = INIT_KEY;

        unsigned long long hk0 = INIT_KEY, hk1 = INIT_KEY, d16k = INIT_KEY;
        bool done = false;
        int mStart = 0;

        if (useLds) {
            for (int base = 0; base < totalPad; base += 64) {
                float4 cvec[8];
                #pragma unroll
                for (int i = 0; i < 8; ++i) cvec[i] = tile[base + 8 * i + l8];
                #pragma unroll
                for (int i = 0; i < 8; ++i) EVAL_INSERT(cvec[i]);
            }
            MERGE_RECORD(hk0, hk1, d16k);       // exact merged top-16
            float d16 = unkey((unsigned int)(d16k >> 32));
            double Rl = (cx - 1 > 0)     ? (xqd - (double)(cx - 1) * CELL_W) : INFINITY;
            double Rr = (cx + 1 < G - 1) ? ((double)(cx + 2) * CELL_W - xqd) : INFINITY;
            double Rb = (cy - 1 > 0)     ? (yqd - (double)(cy - 1) * CELL_W) : INFINITY;
            double Rt = (cy + 1 < G - 1) ? ((double)(cy + 2) * CELL_W - yqd) : INFINITY;
            double R  = fmin(fmin(Rl, Rr), fmin(Rb, Rt)) - 1e-7;
            done = ((double)d16 <= R * R - 1e-5);
            mStart = 2;
            if (!done) {                         // reseed with this lane's two ranks
                bk[0] = hk0; bk[1] = hk1;
                #pragma unroll
                for (int i = 2; i < KSEL; ++i) bk[i] = INIT_KEY;
            }
        }

        if (!done) {                             // rare (prob ~1e-4): global ring scan
            for (int m = mStart; m < G && !done; ++m) {
                int rx0 = max(cx - m, 0), rx1 = min(cx + m, G - 1);
                if (cy - m >= 0) {
                    int cb_ = cs[(cy - m) * G + rx0], ce_ = cs[(cy - m) * G + rx1 + 1];
                    for (int t = cb_ + l8; t < ce_; t += 8) EVAL_INSERT(pb[t]);
                }
                if (m > 0 && cy + m <= G - 1) {
                    int cb_ = cs[(cy + m) * G + rx0], ce_ = cs[(cy + m) * G + rx1 + 1];
                    for (int t = cb_ + l8; t < ce_; t += 8) EVAL_INSERT(pb[t]);
                }
                if (m > 0) {
                    int yA = max(cy - m + 1, 0), yB = min(cy + m - 1, G - 1);
                    if (cx - m >= 0)
                        for (int yy = yA; yy <= yB; ++yy) {
                            int cb_ = cs[yy * G + (cx - m)], ce_ = cs[yy * G + (cx - m) + 1];
                            for (int t = cb_ + l8; t < ce_; t += 8) EVAL_INSERT(pb[t]);
                        }
                    if (cx + m <= G - 1)
                        for (int yy = yA; yy <= yB; ++yy) {
                            int cb_ = cs[yy * G + (cx + m)], ce_ = cs[yy * G + (cx + m) + 1];
                            for (int t = cb_ + l8; t < ce_; t += 8) EVAL_INSERT(pb[t]);
                        }
                }
                float t15 = unkey((unsigned int)(bk[KSEL-1] >> 32));
                t15 = fminf(t15, __shfl_xor(t15, 1));
                t15 = fminf(t15, __shfl_xor(t15, 2));
                t15 = fminf(t15, __shfl_xor(t15, 4));
                float t1 = unkey((unsigned int)(bk[1] >> 32));
                t1 = fmaxf(t1, __shfl_xor(t1, 1));
                t1 = fmaxf(t1, __shfl_xor(t1, 2));
                t1 = fmaxf(t1, __shfl_xor(t1, 4));
                float ub = fminf(t15, t1);
                double Rl = (cx - m > 0)     ? (xqd - (double)(cx - m) * CELL_W)     : INFINITY;
                double Rr = (cx + m < G - 1) ? ((double)(cx + m + 1) * CELL_W - xqd) : INFINITY;
                double Rb = (cy - m > 0)     ? (yqd - (double)(cy - m) * CELL_W)     : INFINITY;
                double Rt = (cy + m < G - 1) ? ((double)(cy + m + 1) * CELL_W - yqd) : INFINITY;
                double R  = fmin(fmin(Rl, Rr), fmin(Rb, Rt)) - 1e-7;
                if ((double)ub <= R * R - 1e-5) done = true;
            }
            MERGE_RECORD(hk0, hk1, d16k);        // re-merge (simultaneous-pop dedupes)
        }

        float v0 = (float)(int)(unsigned int)hk0;
        float v1 = (float)(int)(unsigned int)hk1;
        float* o = out_knn + ((size_t)b * NPTS + qorig) * KSEL;
        *(float2*)(o + 2 * l8) = make_float2(v0, v1);     // 8 lanes cover the 64B line
    }
}

// ---------------- launch ----------------
extern "C" void kernel_launch(void* const* d_in, const int* in_sizes, int n_in,
                              void* d_out, int out_size, void* d_ws, size_t ws_size,
                              hipStream_t stream) {
    const float* coords   = (const float*)d_in[0];
    const float* demands  = (const float*)d_in[1];
    const float* capacity = (const float*)d_in[2];
    const float* curpos   = (const float*)d_in[3];
    const float* Wa       = (const float*)d_in[4];
    const float* ba       = (const float*)d_in[5];
    const float* W1       = (const float*)d_in[6];
    const float* b1       = (const float*)d_in[7];
    const float* W2       = (const float*)d_in[8];
    const float* b2       = (const float*)d_in[9];
    // d_in[10] = knn_k (always 16, hardcoded)

    float* out      = (float*)d_out;
    float* out_psi  = out;                    // 4*8192*2  = 65536
    float* out_feat = out + 65536;            // 4*8192*6  = 196608
    float* out_knn  = out + 65536 + 196608;   // 4*8192*16 = 524288

    int*    cellStart = (int*)   ((char*)d_ws + WS_CSTRT);
    int*    cursor    = (int*)   ((char*)d_ws + WS_CURS);
    float4* pts       = (float4*)((char*)d_ws + WS_PTS);

    grid_hist_scan_kernel<<<dim3(BATCH), dim3(256), 0, stream>>>(coords, cellStart, cursor);

    feat_scatter_kernel<<<dim3((BATCH * NPTS) / 256), dim3(256), 0, stream>>>(
        coords, demands, capacity, curpos, Wa, ba, W1, b1, W2, b2,
        out_psi, out_feat, cursor, pts);

    knn_cell_kernel<<<dim3(NC, BATCH, 2), dim3(128), 0, stream>>>(cellStart, pts, out_knn);
}